// Round 9
// baseline (63.149 us; speedup 1.0000x reference)
//
#include <hip/hip_runtime.h>

// Shapes fixed by the reference: B=1, S=4096, H=32, D=128, M=4096.
#define HH 32
#define DD 128
#define MM 4096
#define ROW_F4 1024          // H*D/4 float4 per token row
#define D_F4   32            // D/4 float4 per (h, m) row
#define CHUNK  32            // tokens per block

typedef float v4f __attribute__((ext_vector_type(4)));

__device__ __forceinline__ int src_token(int m, int cpm, int S) {
    int s0 = m - cpm; if (s0 < 0) s0 += MM;
    return (s0 < S) ? (s0 + MM * ((S - 1 - s0) >> 12)) : -1;   // MM = 2^12
}

// Block = (tensor, 32 consecutive cache positions).
// Phase 1: stream the block's contiguous 512KB input span, per-token amax
//          (wave per row, 8 rows each), scales -> LDS.  No data retained.
// Phase 2: wave owns 8 h-planes; re-reads inputs transposed (L3-hot: the
//          whole grid's phase 1 just installed all 132MB into the 256MB L3)
//          and writes 16KB CONTIGUOUS per h-plane -- the R6-pass-B pattern
//          that ran at ~6TB/s vs ~4.2TB/s for 512B/2KB scattered granules.
__global__ __launch_bounds__(256, 1)
void teleport_fused2(const float* __restrict__ kin,
                     const float* __restrict__ vin,
                     const float* __restrict__ unc,
                     const float* __restrict__ kc_in,
                     const float* __restrict__ vc_in,
                     const float* __restrict__ ksc_in,
                     const float* __restrict__ vsc_in,
                     const int*   __restrict__ cur_pos,
                     float* __restrict__ kc_out,
                     float* __restrict__ vc_out,
                     float* __restrict__ ksc_out,
                     float* __restrict__ vsc_out,
                     int S)
{
    __shared__ float sc_l[CHUNK];
    __shared__ float rc_l[CHUNK];
    __shared__ int   s_l [CHUNK];

    const int t    = threadIdx.x;
    const int lane = t & 63;
    const int wv   = t >> 6;                 // 0..3
    const int b    = blockIdx.x;
    const int isV  = b & 1;
    const int mb   = (b >> 1) * CHUNK;

    const float* in_  = isV ? vin : kin;
    const float* cin  = isV ? vc_in : kc_in;
    float*       cout = isV ? vc_out : kc_out;
    const float* sin_ = isV ? vsc_in  : ksc_in;
    float*       sout = isV ? vsc_out : ksc_out;

    int cp  = *cur_pos;
    int cpm = cp % MM; if (cpm < 0) cpm += MM;

    // ---------------- Phase 1: scales (pure contiguous read) ----------------
    for (int j = 0; j < 8; ++j) {
        const int ml = wv + 4 * j;           // waves interleave -> sliding window
        const int m  = mb + ml;
        const int s  = src_token(m, cpm, S);
        if (s >= 0) {
            const v4f* src = reinterpret_cast<const v4f*>(in_) + (size_t)s * ROW_F4;
            float am0 = 0.0f, am1 = 0.0f;
            #pragma unroll
            for (int c = 0; c < 16; c += 2) {
                v4f a = src[c * 64 + lane];
                v4f d = src[(c + 1) * 64 + lane];
                am0 = fmaxf(am0, fmaxf(fmaxf(fabsf(a.x), fabsf(a.y)),
                                       fmaxf(fabsf(a.z), fabsf(a.w))));
                am1 = fmaxf(am1, fmaxf(fmaxf(fabsf(d.x), fabsf(d.y)),
                                       fmaxf(fabsf(d.z), fabsf(d.w))));
            }
            float am = fmaxf(am0, am1);
            #pragma unroll
            for (int off = 32; off > 0; off >>= 1)
                am = fmaxf(am, __shfl_xor(am, off, 64));
            if (lane == 0) {
                const float u   = unc[s];
                const float div = (u > 0.1f) ? 224.0f : 448.0f;
                const float sc  = fmaxf(am / div, 1e-8f);
                sc_l[ml] = sc;
                rc_l[ml] = 1.0f / sc;        // <=1ulp vs per-element division
                s_l [ml] = s;
            }
        } else if (lane == 0) {
            s_l[ml] = -1;
        }
    }
    __syncthreads();

    // ------- Phase 2: quantize; 16KB-contiguous write span per h-plane ------
    const int d4  = lane & 31;
    const int hi2 = lane >> 5;               // which of the 2 tokens per instr
    v4f* coutv = reinterpret_cast<v4f*>(cout);
    const v4f* cinv = reinterpret_cast<const v4f*>(cin);
    const v4f* inv  = reinterpret_cast<const v4f*>(in_);

    for (int jj = 0; jj < 8; ++jj) {
        const int h = 8 * wv + jj;
        v4f* ob = coutv + (size_t)h * (MM * D_F4) + (size_t)mb * D_F4;

        v4f a[16];
        #pragma unroll
        for (int i = 0; i < 16; ++i) {
            const int ml = 2 * i + hi2;
            const int s  = s_l[ml];
            a[i] = (s >= 0)
                 ? inv [(size_t)s * ROW_F4 + h * D_F4 + d4]
                 : cinv[(size_t)h * (MM * D_F4) + (size_t)(mb + ml) * D_F4 + d4];
        }
        #pragma unroll
        for (int i = 0; i < 16; ++i) {
            const int ml = 2 * i + hi2;
            v4f q = a[i];
            if (s_l[ml] >= 0) {
                const float r = rc_l[ml];
                q.x = fminf(fmaxf(q.x * r, -448.0f), 448.0f);
                q.y = fminf(fmaxf(q.y * r, -448.0f), 448.0f);
                q.z = fminf(fmaxf(q.z * r, -448.0f), 448.0f);
                q.w = fminf(fmaxf(q.w * r, -448.0f), 448.0f);
            }
            ob[ml * D_F4 + d4] = q;
        }
    }

    // ---------------- scales out: 32 h x 32 m per block ---------------------
    #pragma unroll
    for (int q = 0; q < 4; ++q) {
        const int idx = q * 256 + t;         // 0..1023
        const int h   = idx >> 5;
        const int ml  = idx & 31;
        const int m   = mb + ml;
        sout[h * MM + m] = (s_l[ml] >= 0) ? sc_l[ml] : sin_[h * MM + m];
    }
}

extern "C" void kernel_launch(void* const* d_in, const int* in_sizes, int n_in,
                              void* d_out, int out_size, void* d_ws, size_t ws_size,
                              hipStream_t stream) {
    const float* kin = (const float*)d_in[0];
    const float* vin = (const float*)d_in[1];
    const float* unc = (const float*)d_in[2];
    const float* kc  = (const float*)d_in[3];
    const float* vc  = (const float*)d_in[4];
    const float* ksc = (const float*)d_in[5];
    const float* vsc = (const float*)d_in[6];
    const int*   cp  = (const int*)d_in[7];
    const int S = in_sizes[2];   // B*S with B=1

    float* out  = (float*)d_out;
    float* kco  = out;
    float* vco  = kco + (size_t)HH * MM * DD;
    float* ksco = vco + (size_t)HH * MM * DD;
    float* vsco = ksco + (size_t)HH * MM;

    // 2 tensors x (MM/CHUNK) chunks = 256 blocks (1 per CU).
    teleport_fused2<<<2 * (MM / CHUNK), 256, 0, stream>>>(
        kin, vin, unc, kc, vc, ksc, vsc, cp, kco, vco, ksco, vsco, S);
}